// Round 5
// baseline (1712.731 us; speedup 1.0000x reference)
//
#include <hip/hip_runtime.h>
#include <stdint.h>

#define NMEM 50000
#define NTOT 100000
#define DMEM 96
#define DPRV 128
#define IND  128
#define HID  256
#define LATD 64
#define NEDGE 1000000

__device__ __forceinline__ float bf2f(uint32_t u) {
    union { uint32_t u; float f; } x; x.u = u << 16; return x.f;
}
__device__ __forceinline__ uint32_t f2bf(float f) {
    union { float f; uint32_t u; } x; x.f = f;
    uint32_t r = x.u + 0x7fffu + ((x.u >> 16) & 1u);
    return r >> 16;
}
__device__ __forceinline__ int ld_ei(const int* ei, int idx, int i64) {
    return i64 ? ei[2 * idx] : ei[idx];   // int64 LE low word (values < 2^17)
}

// x[v][c2], x[v][c2+1] where x = [pad(x_member); x_provider]; c2 even.
__device__ __forceinline__ float2 load_x2(const void* xm, const void* xp, int f32in,
                                          int v, int c2) {
    float2 r;
    if (v < NMEM) {
        if (c2 < DMEM) {
            size_t o = (size_t)v * DMEM + c2;
            if (f32in) { const float* p = (const float*)xm + o; r.x = p[0]; r.y = p[1]; }
            else {
                uint32_t q = *(const uint32_t*)((const uint16_t*)xm + o);
                r.x = bf2f(q & 0xffffu); r.y = bf2f(q >> 16);
            }
        } else { r.x = 0.f; r.y = 0.f; }
    } else {
        size_t o = (size_t)(v - NMEM) * DPRV + c2;
        if (f32in) { const float* p = (const float*)xp + o; r.x = p[0]; r.y = p[1]; }
        else {
            uint32_t q = *(const uint32_t*)((const uint16_t*)xp + o);
            r.x = bf2f(q & 0xffffu); r.y = bf2f(q >> 16);
        }
    }
    return r;
}

// flags[0]=inputs-are-f32, flags[1]=edge-index-is-int64
__global__ void k_detect(const uint16_t* __restrict__ w1l, const int* __restrict__ ei,
                         int* __restrict__ flags) {
    __shared__ int c1, c2;
    if (threadIdx.x == 0) { c1 = 0; c2 = 0; }
    __syncthreads();
    int big = 0;
    for (int i = threadIdx.x; i < 32768; i += 256) {
        float w = bf2f(w1l[i]);
        if (!(w > -2.0f && w < 2.0f)) big++;        // counts NaN too
    }
    int zhi = 0;
    for (int j = threadIdx.x; j < 2048; j += 256)
        if (ei[2 * j + 1] == 0) zhi++;
    atomicAdd(&c1, big);
    atomicAdd(&c2, zhi);
    __syncthreads();
    if (threadIdx.x == 0) {
        flags[0] = (c1 > 64) ? 1 : 0;
        flags[1] = (c2 > 1024) ? 1 : 0;
    }
}

// Canonicalize all weights/biases to f32 scratch.
// Offsets (floats): W1l 0, W1r 32768, b1 65536, W2l 65792, W2r 82176,
//                   b2 98560, Wd 98624, bd 106816; total 106944.
__global__ void k_canonf(const void* w1l, const void* w1r, const void* b1,
                         const void* w2l, const void* w2r, const void* b2,
                         const void* wd, const void* bd,
                         float* __restrict__ dst, const int* __restrict__ flags) {
    int g = blockIdx.x * 256 + threadIdx.x;
    if (g >= 106944) return;
    const void* src; int off;
    if      (g < 32768)  { src = w1l; off = g; }
    else if (g < 65536)  { src = w1r; off = g - 32768; }
    else if (g < 65792)  { src = b1;  off = g - 65536; }
    else if (g < 82176)  { src = w2l; off = g - 65792; }
    else if (g < 98560)  { src = w2r; off = g - 82176; }
    else if (g < 98624)  { src = b2;  off = g - 98560; }
    else if (g < 106816) { src = wd;  off = g - 98624; }
    else                 { src = bd;  off = g - 106816; }
    dst[g] = flags[0] ? ((const float*)src)[off] : bf2f(((const uint16_t*)src)[off]);
}

__global__ void k_count(const int* __restrict__ ei, int* __restrict__ cnt,
                        const int* __restrict__ flags) {
    int j = blockIdx.x * 256 + threadIdx.x;
    if (j >= NEDGE) return;
    int i64 = flags[1];
    int p = ld_ei(ei, j, i64), m = ld_ei(ei, NEDGE + j, i64);
    atomicAdd(&cnt[NMEM + m], 1);   // ref: dst first half  = member_idx + NM
    atomicAdd(&cnt[p], 1);          // ref: dst second half = provider_idx (raw)
}

__global__ void k_scan1(int* __restrict__ cnt, int* __restrict__ bsum) {
    __shared__ int s[1024];
    int t = threadIdx.x, i = blockIdx.x * 1024 + t;
    int v = (i < NTOT) ? cnt[i] : 0;
    s[t] = v; __syncthreads();
    for (int off = 1; off < 1024; off <<= 1) {
        int x = (t >= off) ? s[t - off] : 0;
        __syncthreads();
        s[t] += x;
        __syncthreads();
    }
    if (i < NTOT) cnt[i] = s[t] - v;
    if (t == 1023) bsum[blockIdx.x] = s[1023];
}
__global__ void k_scan2(int* __restrict__ bsum) {
    __shared__ int s[128];
    int t = threadIdx.x;
    int v = (t < 98) ? bsum[t] : 0;
    s[t] = v; __syncthreads();
    for (int off = 1; off < 128; off <<= 1) {
        int x = (t >= off) ? s[t - off] : 0;
        __syncthreads();
        s[t] += x;
        __syncthreads();
    }
    if (t < 98) bsum[t] = s[t] - v;
}
// row_start[i] = global exclusive scan; cursor reuses cnt (in-place).
__global__ void k_scan3(int* __restrict__ cnt, const int* __restrict__ bsum,
                        int* __restrict__ row_start) {
    int i = blockIdx.x * 1024 + threadIdx.x;
    if (i >= NTOT) return;
    int rs = cnt[i] + bsum[i >> 10];
    row_start[i] = rs;
    cnt[i] = rs;                       // becomes the fill cursor
    if (i == 0) row_start[NTOT] = 2 * NEDGE;
}

__global__ void k_fill(const int* __restrict__ ei, int* __restrict__ cursor,
                       int* __restrict__ colg, const int* __restrict__ flags) {
    int j = blockIdx.x * 256 + threadIdx.x;
    if (j >= NEDGE) return;
    int i64 = flags[1];
    int p = ld_ei(ei, j, i64), m = ld_ei(ei, NEDGE + j, i64);
    int pos1 = atomicAdd(&cursor[NMEM + m], 1); colg[pos1] = p;         // src = p
    int pos2 = atomicAdd(&cursor[p], 1);        colg[pos2] = NMEM + m;  // src = NM+m
}

// GEMM1 (fused agg1): per block 16 rows, full N=256.
// h[r] = relu([agg1(r) | x(r)] @ [W1l|W1r]^T + b1) -> H bf16 [NTOT,256].
__global__ __launch_bounds__(256) void k_vgemm1(const void* xm, const void* xp,
                                                const int* __restrict__ row_start,
                                                const int* __restrict__ colg,
                                                const float* __restrict__ canonf,
                                                uint16_t* __restrict__ H,
                                                const int* __restrict__ flags) {
    __shared__ float ldsA[16][257];    // k 0..127 = agg1, 128..255 = x
    __shared__ float ldsW[256][33];    // 32-wide K chunk of [W1l|W1r]
    int t = threadIdx.x;
    int r0 = blockIdx.x * 16;          // 6250 blocks x 16 = 100000 exact
    int f32in = flags[0];
    int wave = t >> 6, lane = t & 63;
    // Gather: wave handles rows 4*wave..+3; lane sums x-cols 2l,2l+1.
    for (int i = 0; i < 4; i++) {
        int v = r0 + 4 * wave + i;
        int start = row_start[v], end = row_start[v + 1];
        float s0 = 0.f, s1 = 0.f;
        for (int b = start; b < end; b += 64) {
            int myc = (b + lane < end) ? colg[b + lane] : 0;
            int n = min(end - b, 64);
            for (int u = 0; u < n; u++) {
                int src = __shfl(myc, u);
                float2 xv = load_x2(xm, xp, f32in, src, 2 * lane);
                s0 += xv.x; s1 += xv.y;
            }
        }
        float inv = 1.0f / (float)max(end - start, 1);
        ldsA[4 * wave + i][2 * lane]     = s0 * inv;
        ldsA[4 * wave + i][2 * lane + 1] = s1 * inv;
    }
    // Stage own x rows into k 128..255.
    for (int idx = t; idx < 1024; idx += 256) {       // 16 rows x 64 pairs
        int r = idx >> 6, c2 = (idx & 63) * 2;
        float2 xv = load_x2(xm, xp, f32in, r0 + r, c2);
        ldsA[r][128 + c2]     = xv.x;
        ldsA[r][128 + c2 + 1] = xv.y;
    }
    int row = t & 15, grp = t >> 4;    // thread: row, cols grp*16+i
    float acc[16];
#pragma unroll
    for (int i = 0; i < 16; i++) acc[i] = canonf[65536 + grp * 16 + i];   // b1
    const float* W1l = canonf;
    const float* W1r = canonf + 32768;
    for (int ch = 0; ch < 8; ch++) {
        __syncthreads();               // covers ldsA writes before ch=0 too
        for (int idx = t; idx < 8192; idx += 256) {   // 256 cols x 32 k
            int c = idx >> 5, j = idx & 31;
            int k = ch * 32 + j;
            ldsW[c][j] = (k < 128) ? W1l[c * 128 + k] : W1r[c * 128 + (k - 128)];
        }
        __syncthreads();
#pragma unroll 8
        for (int j = 0; j < 32; j++) {
            float a = ldsA[row][ch * 32 + j];
#pragma unroll
            for (int i = 0; i < 16; i++)
                acc[i] += a * ldsW[grp * 16 + i][j];
        }
    }
#pragma unroll
    for (int i = 0; i < 16; i++)
        H[(size_t)(r0 + row) * 256 + grp * 16 + i] =
            (uint16_t)f2bf(fmaxf(acc[i], 0.f));
}

// GEMM2 (fused agg2): per block 16 rows, N=64.
// z[r] = [agg2(r) | h(r)] @ [W2l|W2r]^T + b2 -> Zbf bf16 [NTOT,64].
__global__ __launch_bounds__(256) void k_vgemm2(const uint16_t* __restrict__ H,
                                                const int* __restrict__ row_start,
                                                const int* __restrict__ colg,
                                                const float* __restrict__ canonf,
                                                uint16_t* __restrict__ Zbf) {
    __shared__ float ldsA[16][514];    // k 0..255 = agg2, 256..511 = h
    __shared__ float ldsW[64][33];
    int t = threadIdx.x;
    int r0 = blockIdx.x * 16;
    int wave = t >> 6, lane = t & 63;
    for (int i = 0; i < 4; i++) {
        int v = r0 + 4 * wave + i;
        int start = row_start[v], end = row_start[v + 1];
        float s0 = 0.f, s1 = 0.f, s2 = 0.f, s3 = 0.f;
        for (int b = start; b < end; b += 64) {
            int myc = (b + lane < end) ? colg[b + lane] : 0;
            int n = min(end - b, 64);
            for (int u = 0; u < n; u++) {
                int src = __shfl(myc, u);
                uint2 q = *(const uint2*)(H + (size_t)src * 256 + 4 * lane);
                s0 += bf2f(q.x & 0xffffu); s1 += bf2f(q.x >> 16);
                s2 += bf2f(q.y & 0xffffu); s3 += bf2f(q.y >> 16);
            }
        }
        float inv = 1.0f / (float)max(end - start, 1);
        int rr = 4 * wave + i;
        ldsA[rr][4 * lane + 0] = s0 * inv;
        ldsA[rr][4 * lane + 1] = s1 * inv;
        ldsA[rr][4 * lane + 2] = s2 * inv;
        ldsA[rr][4 * lane + 3] = s3 * inv;
    }
    for (int idx = t; idx < 4096; idx += 256) {       // 16 rows x 256 cols
        int r = idx >> 8, c = idx & 255;
        ldsA[r][256 + c] = bf2f(H[(size_t)(r0 + r) * 256 + c]);
    }
    int row = t & 15, grp = t >> 4;    // cols grp*4+i
    float acc[4];
#pragma unroll
    for (int i = 0; i < 4; i++) acc[i] = canonf[98560 + grp * 4 + i];     // b2
    const float* W2l = canonf + 65792;
    const float* W2r = canonf + 82176;
    for (int ch = 0; ch < 16; ch++) {
        __syncthreads();
        for (int idx = t; idx < 2048; idx += 256) {   // 64 cols x 32 k
            int c = idx >> 5, j = idx & 31;
            int k = ch * 32 + j;
            ldsW[c][j] = (k < 256) ? W2l[c * 256 + k] : W2r[c * 256 + (k - 256)];
        }
        __syncthreads();
#pragma unroll 8
        for (int j = 0; j < 32; j++) {
            float a = ldsA[row][ch * 32 + j];
#pragma unroll
            for (int i = 0; i < 4; i++)
                acc[i] += a * ldsW[grp * 4 + i][j];
        }
    }
#pragma unroll
    for (int i = 0; i < 4; i++)
        Zbf[(size_t)(r0 + row) * 64 + grp * 4 + i] = (uint16_t)f2bf(acc[i]);
}

// GEMM3: x_hat = z @ Wd^T + bd -> d_out FLOAT32 [NTOT,128].
__global__ __launch_bounds__(256) void k_vgemm3(const uint16_t* __restrict__ Zbf,
                                                const float* __restrict__ canonf,
                                                float* __restrict__ outf) {
    __shared__ float ldsZ[16][65];
    __shared__ float ldsW[128][65];
    int t = threadIdx.x;
    int r0 = blockIdx.x * 16;
    for (int idx = t; idx < 1024; idx += 256) {       // 16 x 64
        int r = idx >> 6, c = idx & 63;
        ldsZ[r][c] = bf2f(Zbf[(size_t)(r0 + r) * 64 + c]);
    }
    for (int idx = t; idx < 8192; idx += 256) {       // 128 x 64
        int c = idx >> 6, k = idx & 63;
        ldsW[c][k] = canonf[98624 + c * 64 + k];      // Wd
    }
    __syncthreads();
    int row = t & 15, grp = t >> 4;    // cols grp*8+i
    float acc[8];
#pragma unroll
    for (int i = 0; i < 8; i++) acc[i] = canonf[106816 + grp * 8 + i];    // bd
    for (int k = 0; k < 64; k++) {
        float a = ldsZ[row][k];
#pragma unroll
        for (int i = 0; i < 8; i++) acc[i] += a * ldsW[grp * 8 + i][k];
    }
#pragma unroll
    for (int i = 0; i < 8; i++)
        outf[(size_t)(r0 + row) * 128 + grp * 8 + i] = acc[i];
}

// edge_logits[j] = dot64(z[NM+p], z[m]) -> FLOAT32; 16 lanes/edge.
__global__ void k_logits(const int* __restrict__ ei, const uint16_t* __restrict__ z,
                         float* __restrict__ out, const int* __restrict__ flags) {
    int t = blockIdx.x * 256 + threadIdx.x;
    int j = t >> 4, sub = t & 15;
    if (j >= NEDGE) return;
    int i64 = flags[1];
    int p = ld_ei(ei, j, i64), m = ld_ei(ei, NEDGE + j, i64);
    uint2 a = *(const uint2*)(z + (size_t)(NMEM + p) * 64 + 4 * sub);
    uint2 b = *(const uint2*)(z + (size_t)m * 64 + 4 * sub);
    float d = bf2f(a.x & 0xffffu) * bf2f(b.x & 0xffffu)
            + bf2f(a.x >> 16)     * bf2f(b.x >> 16)
            + bf2f(a.y & 0xffffu) * bf2f(b.y & 0xffffu)
            + bf2f(a.y >> 16)     * bf2f(b.y >> 16);
#pragma unroll
    for (int k = 8; k >= 1; k >>= 1) d += __shfl_xor(d, k);
    if (sub == 0) out[j] = d;
}

// Sentinel path (ws too small): zero output, encode ws_MB + flags in out[0].
__global__ void k_zero_out(float* __restrict__ out, int n4) {
    int i = blockIdx.x * 256 + threadIdx.x;
    if (i < n4) ((uint4*)out)[i] = (uint4){0, 0, 0, 0};
}
__global__ void k_sentinel(float* __restrict__ out, const int* __restrict__ flags,
                           int ws_mb) {
    if (blockIdx.x == 0 && threadIdx.x == 0)
        out[0] = 1000.0f + (float)ws_mb + 4096.0f * flags[0] + 8192.0f * flags[1];
}

extern "C" void kernel_launch(void* const* d_in, const int* in_sizes, int n_in,
                              void* d_out, int out_size, void* d_ws, size_t ws_size,
                              hipStream_t stream) {
    const void* xm = d_in[0];
    const void* xp = d_in[1];
    const int*  ei = (const int*)d_in[2];
    float* outf = (float*)d_out;                      // OUTPUT IS FLOAT32

    const size_t NEED = 73232640;
    if (ws_size < NEED) {
        int* flags = (int*)d_ws;
        k_detect<<<1, 256, 0, stream>>>((const uint16_t*)d_in[3], ei, flags);
        int n4 = out_size / 4;
        k_zero_out<<<(n4 + 255) / 256, 256, 0, stream>>>(outf, n4);
        k_sentinel<<<1, 64, 0, stream>>>(outf, flags, (int)(ws_size >> 20));
        return;
    }

    // Layout (73,232,640 B total):
    char* ws = (char*)d_ws;
    int* colg      = (int*)(ws + 0);              //  8,000,000
    int* cnt       = (int*)(ws + 8000000);        //    400,384 (becomes cursor)
    int* row_start = (int*)(ws + 8400384);        //    400,384
    int* bsum      = (int*)(ws + 8800768);        //      4,096 (flags at +100)
    int* flags     = bsum + 100;
    float* canonf  = (float*)(ws + 8804864);      //    427,776 (weights f32)
    uint16_t* H    = (uint16_t*)(ws + 9232640);   // 51,200,000 (h bf16)
    uint16_t* Zbf  = (uint16_t*)(ws + 60432640);  // 12,800,000 (z bf16)

    k_detect<<<1, 256, 0, stream>>>((const uint16_t*)d_in[3], ei, flags);
    k_canonf<<<418, 256, 0, stream>>>(d_in[3], d_in[4], d_in[5], d_in[6], d_in[7],
                                      d_in[8], d_in[9], d_in[10], canonf, flags);
    hipMemsetAsync(cnt, 0, NTOT * sizeof(int), stream);
    k_count<<<(NEDGE + 255) / 256, 256, 0, stream>>>(ei, cnt, flags);
    k_scan1<<<98, 1024, 0, stream>>>(cnt, bsum);
    k_scan2<<<1, 128, 0, stream>>>(bsum);
    k_scan3<<<98, 1024, 0, stream>>>(cnt, bsum, row_start);
    k_fill<<<(NEDGE + 255) / 256, 256, 0, stream>>>(ei, cnt, colg, flags);
    k_vgemm1<<<6250, 256, 0, stream>>>(xm, xp, row_start, colg, canonf, H, flags);
    k_vgemm2<<<6250, 256, 0, stream>>>(H, row_start, colg, canonf, Zbf);
    k_vgemm3<<<6250, 256, 0, stream>>>(Zbf, canonf, outf);
    k_logits<<<62500, 256, 0, stream>>>(ei, Zbf, outf + 12800000, flags);
}

// Round 6
// 777.311 us; speedup vs baseline: 2.2034x; 2.2034x over previous
//
#include <hip/hip_runtime.h>
#include <stdint.h>

#define NMEM 50000
#define NTOT 100000
#define DMEM 96
#define DPRV 128
#define IND  128
#define HID  256
#define LATD 64
#define NEDGE 1000000

typedef __bf16 v8bf  __attribute__((ext_vector_type(8)));
typedef float  f32x4 __attribute__((ext_vector_type(4)));

__device__ __forceinline__ float bf2f(uint32_t u) {
    union { uint32_t u; float f; } x; x.u = u << 16; return x.f;
}
__device__ __forceinline__ uint32_t f2bf(float f) {
    union { float f; uint32_t u; } x; x.f = f;
    uint32_t r = x.u + 0x7fffu + ((x.u >> 16) & 1u);
    return r >> 16;
}
__device__ __forceinline__ int ld_ei(const int* ei, int idx, int i64) {
    return i64 ? ei[2 * idx] : ei[idx];
}

// flags[0]=inputs-are-f32, flags[1]=edge-index-is-int64
__global__ void k_detect(const uint16_t* __restrict__ w1l, const int* __restrict__ ei,
                         int* __restrict__ flags) {
    __shared__ int c1, c2;
    if (threadIdx.x == 0) { c1 = 0; c2 = 0; }
    __syncthreads();
    int big = 0;
    for (int i = threadIdx.x; i < 32768; i += 256) {
        float w = bf2f(w1l[i]);
        if (!(w > -2.0f && w < 2.0f)) big++;
    }
    int zhi = 0;
    for (int j = threadIdx.x; j < 2048; j += 256)
        if (ei[2 * j + 1] == 0) zhi++;
    atomicAdd(&c1, big);
    atomicAdd(&c2, zhi);
    __syncthreads();
    if (threadIdx.x == 0) {
        flags[0] = (c1 > 64) ? 1 : 0;
        flags[1] = (c2 > 1024) ? 1 : 0;
    }
}

// Weights -> bf16 canon: W1cat [256][256] @0 (k<128 W1l else W1r),
// W2l [64][256] @65536, W2r [64][256] @81920, Wd [128][64] @98304.
// Biases -> f32: b1 @0, b2 @256, bd @320 (448 total).
__global__ void k_canon(const void* w1l, const void* w1r, const void* w2l,
                        const void* w2r, const void* wd, const void* b1,
                        const void* b2, const void* bd,
                        uint16_t* __restrict__ dstw, float* __restrict__ dstb,
                        const int* __restrict__ flags) {
    int g = blockIdx.x * 256 + threadIdx.x;
    int f32in = flags[0];
    if (g < 106496) {
        const void* src; int off;
        if (g < 65536) { int n = g >> 8, k = g & 255;
            src = (k < 128) ? w1l : w1r; off = n * 128 + (k & 127); }
        else if (g < 81920) { src = w2l; off = g - 65536; }
        else if (g < 98304) { src = w2r; off = g - 81920; }
        else                { src = wd;  off = g - 98304; }
        dstw[g] = f32in ? (uint16_t)f2bf(((const float*)src)[off])
                        : ((const uint16_t*)src)[off];
    } else if (g < 106944) {
        int o = g - 106496;
        const void* src; int off;
        if (o < 256)      { src = b1; off = o; }
        else if (o < 320) { src = b2; off = o - 256; }
        else              { src = bd; off = o - 320; }
        dstb[o] = f32in ? ((const float*)src)[off] : bf2f(((const uint16_t*)src)[off]);
    }
}

// ---------------- CSR build (verified round 5) ----------------
__global__ void k_count(const int* __restrict__ ei, int* __restrict__ cnt,
                        const int* __restrict__ flags) {
    int j = blockIdx.x * 256 + threadIdx.x;
    if (j >= NEDGE) return;
    int i64 = flags[1];
    int p = ld_ei(ei, j, i64), m = ld_ei(ei, NEDGE + j, i64);
    atomicAdd(&cnt[NMEM + m], 1);
    atomicAdd(&cnt[p], 1);
}
__global__ void k_scan1(int* __restrict__ cnt, int* __restrict__ bsum) {
    __shared__ int s[1024];
    int t = threadIdx.x, i = blockIdx.x * 1024 + t;
    int v = (i < NTOT) ? cnt[i] : 0;
    s[t] = v; __syncthreads();
    for (int off = 1; off < 1024; off <<= 1) {
        int x = (t >= off) ? s[t - off] : 0;
        __syncthreads();
        s[t] += x;
        __syncthreads();
    }
    if (i < NTOT) cnt[i] = s[t] - v;
    if (t == 1023) bsum[blockIdx.x] = s[1023];
}
__global__ void k_scan2(int* __restrict__ bsum) {
    __shared__ int s[128];
    int t = threadIdx.x;
    int v = (t < 98) ? bsum[t] : 0;
    s[t] = v; __syncthreads();
    for (int off = 1; off < 128; off <<= 1) {
        int x = (t >= off) ? s[t - off] : 0;
        __syncthreads();
        s[t] += x;
        __syncthreads();
    }
    if (t < 98) bsum[t] = s[t] - v;
}
__global__ void k_scan3(int* __restrict__ cnt, const int* __restrict__ bsum,
                        int* __restrict__ row_start) {
    int i = blockIdx.x * 1024 + threadIdx.x;
    if (i >= NTOT) return;
    int rs = cnt[i] + bsum[i >> 10];
    row_start[i] = rs;
    cnt[i] = rs;                       // becomes the fill cursor
    if (i == 0) row_start[NTOT] = 2 * NEDGE;
}
__global__ void k_fill(const int* __restrict__ ei, int* __restrict__ cursor,
                       int* __restrict__ colg, const int* __restrict__ flags) {
    int j = blockIdx.x * 256 + threadIdx.x;
    if (j >= NEDGE) return;
    int i64 = flags[1];
    int p = ld_ei(ei, j, i64), m = ld_ei(ei, NEDGE + j, i64);
    int pos1 = atomicAdd(&cursor[NMEM + m], 1); colg[pos1] = p;
    int pos2 = atomicAdd(&cursor[p], 1);        colg[pos2] = NMEM + m;
}

// 8 bf16 of concat-x row: x[row][k..k+7], k multiple of 8 (<128).
__device__ __forceinline__ v8bf load_xfrag(const void* xm, const void* xp,
                                           int f32in, int row, int k) {
    union { v8bf v; uint16_t u[8]; uint4 q; } r;
    if (row < NMEM) {
        if (k < DMEM) {
            if (f32in) {
                const float* p = (const float*)xm + (size_t)row * DMEM + k;
                float4 f0 = *(const float4*)p, f1 = *(const float4*)(p + 4);
                r.u[0] = f2bf(f0.x); r.u[1] = f2bf(f0.y); r.u[2] = f2bf(f0.z);
                r.u[3] = f2bf(f0.w); r.u[4] = f2bf(f1.x); r.u[5] = f2bf(f1.y);
                r.u[6] = f2bf(f1.z); r.u[7] = f2bf(f1.w);
            } else
                r.q = *(const uint4*)((const uint16_t*)xm + (size_t)row * DMEM + k);
        } else r.q = (uint4){0, 0, 0, 0};
    } else {
        size_t o = (size_t)(row - NMEM) * DPRV + k;
        if (f32in) {
            const float* p = (const float*)xp + o;
            float4 f0 = *(const float4*)p, f1 = *(const float4*)(p + 4);
            r.u[0] = f2bf(f0.x); r.u[1] = f2bf(f0.y); r.u[2] = f2bf(f0.z);
            r.u[3] = f2bf(f0.w); r.u[4] = f2bf(f1.x); r.u[5] = f2bf(f1.y);
            r.u[6] = f2bf(f1.z); r.u[7] = f2bf(f1.w);
        } else
            r.q = *(const uint4*)((const uint16_t*)xp + o);
    }
    return r.v;
}

// agg1: A1[v] = mean of x rows over nb(v). Wave = 4 neighbor-slots x 16
// col-groups (16 B each). Parallel loads, cross-slot shfl reduction.
__global__ __launch_bounds__(256) void k_agg1(const void* xm, const void* xp,
                                              const int* __restrict__ row_start,
                                              const int* __restrict__ colg,
                                              uint16_t* __restrict__ A1,
                                              const int* __restrict__ flags) {
    int v = blockIdx.x * 4 + (threadIdx.x >> 6);
    int lane = threadIdx.x & 63;
    int slot = lane >> 4, cg = lane & 15;
    int f32in = flags[0];
    int start = row_start[v], end = row_start[v + 1];
    float a[8] = {0.f, 0.f, 0.f, 0.f, 0.f, 0.f, 0.f, 0.f};
    for (int b = start + slot; b < end; b += 4) {
        int src = colg[b];
        union { v8bf v; uint16_t u[8]; } f;
        f.v = load_xfrag(xm, xp, f32in, src, cg * 8);
#pragma unroll
        for (int i = 0; i < 8; i++) a[i] += bf2f(f.u[i]);
    }
#pragma unroll
    for (int i = 0; i < 8; i++) {
        a[i] += __shfl_xor(a[i], 16);
        a[i] += __shfl_xor(a[i], 32);
    }
    if (slot == 0) {
        float inv = 1.0f / (float)max(end - start, 1);
        union { uint4 q; uint16_t u[8]; } o;
#pragma unroll
        for (int i = 0; i < 8; i++) o.u[i] = (uint16_t)f2bf(a[i] * inv);
        *(uint4*)(A1 + (size_t)v * 128 + cg * 8) = o.q;
    }
}

// GEMM1 (MFMA, fused): per wave 16 rows.
//   h  = relu([A1 | x] @ W1cat^T + b1)        (LDS tile, never global)
//   P  = h @ W2l^T                            -> bf16 [NTOT][64]
//   R  = h @ W2r^T + b2                       -> bf16 [NTOT][64]
__global__ __launch_bounds__(256) void k_gemm1(const void* xm, const void* xp,
                                               const uint16_t* __restrict__ A1,
                                               const uint16_t* __restrict__ canonb,
                                               const float* __restrict__ biasf,
                                               uint16_t* __restrict__ P,
                                               uint16_t* __restrict__ R,
                                               const int* __restrict__ flags) {
    __shared__ uint16_t hl[4][16][264];        // +8 pad: conflict-free b128 reads
    int wave = threadIdx.x >> 6, lane = threadIdx.x & 63;
    int m16 = lane & 15, quad = lane >> 4;
    int row0 = (blockIdx.x * 4 + wave) * 16;
    int arow = min(row0 + m16, NTOT - 1);
    int f32in = flags[0];
    f32x4 acc[16];
#pragma unroll
    for (int i = 0; i < 16; i++) acc[i] = (f32x4){0.f, 0.f, 0.f, 0.f};
#pragma unroll
    for (int ks = 0; ks < 8; ks++) {
        v8bf a;
        if (ks < 4) a = *(const v8bf*)(A1 + (size_t)arow * 128 + ks * 32 + quad * 8);
        else        a = load_xfrag(xm, xp, f32in, arow, (ks - 4) * 32 + quad * 8);
#pragma unroll
        for (int nt = 0; nt < 16; nt++) {
            v8bf b = *(const v8bf*)(canonb + (size_t)(nt * 16 + m16) * 256 + ks * 32 + quad * 8);
            acc[nt] = __builtin_amdgcn_mfma_f32_16x16x32_bf16(a, b, acc[nt], 0, 0, 0);
        }
    }
    // h tile -> LDS (relu + bias, bf16). Wave-private: no barrier needed.
#pragma unroll
    for (int nt = 0; nt < 16; nt++) {
        int col = nt * 16 + m16;
        float bia = biasf[col];
#pragma unroll
        for (int r = 0; r < 4; r++)
            hl[wave][quad * 4 + r][col] = (uint16_t)f2bf(fmaxf(acc[nt][r] + bia, 0.f));
    }
    f32x4 accP[4], accR[4];
#pragma unroll
    for (int i = 0; i < 4; i++) {
        accP[i] = (f32x4){0.f, 0.f, 0.f, 0.f};
        accR[i] = (f32x4){0.f, 0.f, 0.f, 0.f};
    }
#pragma unroll
    for (int ks = 0; ks < 8; ks++) {
        v8bf a = *(const v8bf*)&hl[wave][m16][ks * 32 + quad * 8];
#pragma unroll
        for (int nt = 0; nt < 4; nt++) {
            v8bf bl = *(const v8bf*)(canonb + 65536 + (size_t)(nt * 16 + m16) * 256 + ks * 32 + quad * 8);
            v8bf br = *(const v8bf*)(canonb + 81920 + (size_t)(nt * 16 + m16) * 256 + ks * 32 + quad * 8);
            accP[nt] = __builtin_amdgcn_mfma_f32_16x16x32_bf16(a, bl, accP[nt], 0, 0, 0);
            accR[nt] = __builtin_amdgcn_mfma_f32_16x16x32_bf16(a, br, accR[nt], 0, 0, 0);
        }
    }
#pragma unroll
    for (int nt = 0; nt < 4; nt++) {
        int col = nt * 16 + m16;
        float b2 = biasf[256 + col];
#pragma unroll
        for (int r = 0; r < 4; r++) {
            int row = row0 + quad * 4 + r;
            if (row < NTOT) {
                P[(size_t)row * 64 + col] = (uint16_t)f2bf(accP[nt][r]);
                R[(size_t)row * 64 + col] = (uint16_t)f2bf(accR[nt][r] + b2);
            }
        }
    }
}

// agg2z: Z[v] = R[v] + mean of P rows over nb(v). Wave = 8 slots x 8 cgs.
__global__ __launch_bounds__(256) void k_agg2z(const uint16_t* __restrict__ P,
                                               const uint16_t* __restrict__ R,
                                               const int* __restrict__ row_start,
                                               const int* __restrict__ colg,
                                               uint16_t* __restrict__ Z) {
    int v = blockIdx.x * 4 + (threadIdx.x >> 6);
    int lane = threadIdx.x & 63;
    int slot = lane >> 3, cg = lane & 7;
    int start = row_start[v], end = row_start[v + 1];
    float a[8] = {0.f, 0.f, 0.f, 0.f, 0.f, 0.f, 0.f, 0.f};
    for (int b = start + slot; b < end; b += 8) {
        int src = colg[b];
        union { uint4 q; uint16_t u[8]; } f;
        f.q = *(const uint4*)(P + (size_t)src * 64 + cg * 8);
#pragma unroll
        for (int i = 0; i < 8; i++) a[i] += bf2f(f.u[i]);
    }
#pragma unroll
    for (int i = 0; i < 8; i++) {
        a[i] += __shfl_xor(a[i], 8);
        a[i] += __shfl_xor(a[i], 16);
        a[i] += __shfl_xor(a[i], 32);
    }
    if (slot == 0) {
        float inv = 1.0f / (float)max(end - start, 1);
        union { uint4 q; uint16_t u[8]; } rr, o;
        rr.q = *(const uint4*)(R + (size_t)v * 64 + cg * 8);
#pragma unroll
        for (int i = 0; i < 8; i++)
            o.u[i] = (uint16_t)f2bf(a[i] * inv + bf2f(rr.u[i]));
        *(uint4*)(Z + (size_t)v * 64 + cg * 8) = o.q;
    }
}

// GEMM3 (MFMA): x_hat = Z @ Wd^T + bd -> f32 d_out [NTOT][128].
__global__ __launch_bounds__(256) void k_gemm3(const uint16_t* __restrict__ Z,
                                               const uint16_t* __restrict__ canonb,
                                               const float* __restrict__ biasf,
                                               float* __restrict__ outf) {
    int wave = threadIdx.x >> 6, lane = threadIdx.x & 63;
    int m16 = lane & 15, quad = lane >> 4;
    int row0 = (blockIdx.x * 4 + wave) * 16;
    int arow = min(row0 + m16, NTOT - 1);
    f32x4 acc[8];
#pragma unroll
    for (int i = 0; i < 8; i++) acc[i] = (f32x4){0.f, 0.f, 0.f, 0.f};
#pragma unroll
    for (int ks = 0; ks < 2; ks++) {
        v8bf a = *(const v8bf*)(Z + (size_t)arow * 64 + ks * 32 + quad * 8);
#pragma unroll
        for (int nt = 0; nt < 8; nt++) {
            v8bf b = *(const v8bf*)(canonb + 98304 + (size_t)(nt * 16 + m16) * 64 + ks * 32 + quad * 8);
            acc[nt] = __builtin_amdgcn_mfma_f32_16x16x32_bf16(a, b, acc[nt], 0, 0, 0);
        }
    }
#pragma unroll
    for (int nt = 0; nt < 8; nt++) {
        int col = nt * 16 + m16;
        float bia = biasf[320 + col];
#pragma unroll
        for (int r = 0; r < 4; r++) {
            int row = row0 + quad * 4 + r;
            if (row < NTOT) outf[(size_t)row * 128 + col] = acc[nt][r] + bia;
        }
    }
}

// edge_logits[j] = dot64(Z[NM+p], Z[m]) -> f32; 8 lanes/edge, uint4 loads.
__global__ __launch_bounds__(256) void k_logits(const int* __restrict__ ei,
                                                const uint16_t* __restrict__ Z,
                                                float* __restrict__ out,
                                                const int* __restrict__ flags) {
    int t = blockIdx.x * 256 + threadIdx.x;
    int j = t >> 3, sub = t & 7;
    if (j >= NEDGE) return;
    int i64 = flags[1];
    int p = ld_ei(ei, j, i64), m = ld_ei(ei, NEDGE + j, i64);
    union { uint4 q; uint16_t u[8]; } a, b;
    a.q = *(const uint4*)(Z + (size_t)(NMEM + p) * 64 + sub * 8);
    b.q = *(const uint4*)(Z + (size_t)m * 64 + sub * 8);
    float d = 0.f;
#pragma unroll
    for (int i = 0; i < 8; i++) d += bf2f(a.u[i]) * bf2f(b.u[i]);
    d += __shfl_xor(d, 1);
    d += __shfl_xor(d, 2);
    d += __shfl_xor(d, 4);
    if (sub == 0) out[j] = d;
}

// Sentinel path (ws too small): zero output, encode ws_MB + flags in out[0].
__global__ void k_zero_out(float* __restrict__ out, int n4) {
    int i = blockIdx.x * 256 + threadIdx.x;
    if (i < n4) ((uint4*)out)[i] = (uint4){0, 0, 0, 0};
}
__global__ void k_sentinel(float* __restrict__ out, const int* __restrict__ flags,
                           int ws_mb) {
    if (blockIdx.x == 0 && threadIdx.x == 0)
        out[0] = 1000.0f + (float)ws_mb + 4096.0f * flags[0] + 8192.0f * flags[1];
}

extern "C" void kernel_launch(void* const* d_in, const int* in_sizes, int n_in,
                              void* d_out, int out_size, void* d_ws, size_t ws_size,
                              hipStream_t stream) {
    const void* xm = d_in[0];
    const void* xp = d_in[1];
    const int*  ei = (const int*)d_in[2];
    float* outf = (float*)d_out;

    const size_t NEED = 73019648;
    if (ws_size < NEED) {
        int* flags = (int*)d_ws;
        k_detect<<<1, 256, 0, stream>>>((const uint16_t*)d_in[3], ei, flags);
        int n4 = out_size / 4;
        k_zero_out<<<(n4 + 255) / 256, 256, 0, stream>>>(outf, n4);
        k_sentinel<<<1, 64, 0, stream>>>(outf, flags, (int)(ws_size >> 20));
        return;
    }

    // Layout (73,019,648 B):
    char* ws = (char*)d_ws;
    int* colg       = (int*)(ws + 0);              //  8,000,000
    int* cnt        = (int*)(ws + 8000000);        //    400,384 (becomes cursor)
    int* row_start  = (int*)(ws + 8400384);        //    400,384
    int* bsum       = (int*)(ws + 8800768);        //      4,096 (flags at +100 ints)
    int* flags      = (int*)(ws + 8800768) + 100;
    uint16_t* canonb= (uint16_t*)(ws + 8804864);   //    212,992 (bf16 weights)
    float* biasf    = (float*)(ws + 9017856);      //      1,792 (f32 biases)
    uint16_t* A1    = (uint16_t*)(ws + 9019648);   // 25,600,000
    uint16_t* P     = (uint16_t*)(ws + 34619648);  // 12,800,000
    uint16_t* R     = (uint16_t*)(ws + 47419648);  // 12,800,000
    uint16_t* Z     = (uint16_t*)(ws + 60219648);  // 12,800,000

    k_detect<<<1, 256, 0, stream>>>((const uint16_t*)d_in[3], ei, flags);
    k_canon<<<418, 256, 0, stream>>>(d_in[3], d_in[4], d_in[6], d_in[7], d_in[9],
                                     d_in[5], d_in[8], d_in[10], canonb, biasf, flags);
    hipMemsetAsync(cnt, 0, NTOT * sizeof(int), stream);
    k_count<<<(NEDGE + 255) / 256, 256, 0, stream>>>(ei, cnt, flags);
    k_scan1<<<98, 1024, 0, stream>>>(cnt, bsum);
    k_scan2<<<1, 128, 0, stream>>>(bsum);
    k_scan3<<<98, 1024, 0, stream>>>(cnt, bsum, row_start);
    k_fill<<<(NEDGE + 255) / 256, 256, 0, stream>>>(ei, cnt, colg, flags);
    k_agg1<<<NTOT / 4, 256, 0, stream>>>(xm, xp, row_start, colg, A1, flags);
    k_gemm1<<<1563, 256, 0, stream>>>(xm, xp, A1, canonb, biasf, P, R, flags);
    k_agg2z<<<NTOT / 4, 256, 0, stream>>>(P, R, row_start, colg, Z);
    k_gemm3<<<1563, 256, 0, stream>>>(Z, canonb, biasf, outf);
    k_logits<<<NEDGE * 8 / 256, 256, 0, stream>>>(ei, Z, outf + 12800000, flags);
}

// Round 7
// 746.099 us; speedup vs baseline: 2.2956x; 1.0418x over previous
//
#include <hip/hip_runtime.h>
#include <stdint.h>

#define NMEM 50000
#define NTOT 100000
#define DMEM 96
#define DPRV 128
#define IND  128
#define HID  256
#define LATD 64
#define NEDGE 1000000

typedef __bf16 v8bf  __attribute__((ext_vector_type(8)));
typedef float  f32x4 __attribute__((ext_vector_type(4)));

__device__ __forceinline__ float bf2f(uint32_t u) {
    union { uint32_t u; float f; } x; x.u = u << 16; return x.f;
}
__device__ __forceinline__ uint32_t f2bf(float f) {
    union { float f; uint32_t u; } x; x.f = f;
    uint32_t r = x.u + 0x7fffu + ((x.u >> 16) & 1u);
    return r >> 16;
}
__device__ __forceinline__ int ld_ei(const int* ei, int idx, int i64) {
    return i64 ? ei[2 * idx] : ei[idx];
}

// flags[0]=inputs-are-f32, flags[1]=edge-index-is-int64
__global__ void k_detect(const uint16_t* __restrict__ w1l, const int* __restrict__ ei,
                         int* __restrict__ flags) {
    __shared__ int c1, c2;
    if (threadIdx.x == 0) { c1 = 0; c2 = 0; }
    __syncthreads();
    int big = 0;
    for (int i = threadIdx.x; i < 32768; i += 256) {
        float w = bf2f(w1l[i]);
        if (!(w > -2.0f && w < 2.0f)) big++;
    }
    int zhi = 0;
    for (int j = threadIdx.x; j < 2048; j += 256)
        if (ei[2 * j + 1] == 0) zhi++;
    atomicAdd(&c1, big);
    atomicAdd(&c2, zhi);
    __syncthreads();
    if (threadIdx.x == 0) {
        flags[0] = (c1 > 64) ? 1 : 0;
        flags[1] = (c2 > 1024) ? 1 : 0;
    }
}

// Weights -> bf16 canon: W1cat [256][256] @0 (k<128 W1l else W1r),
// W2l [64][256] @65536, W2r [64][256] @81920, Wd [128][64] @98304.
// Biases -> f32: b1 @0, b2 @256, bd @320.
__global__ void k_canon(const void* w1l, const void* w1r, const void* w2l,
                        const void* w2r, const void* wd, const void* b1,
                        const void* b2, const void* bd,
                        uint16_t* __restrict__ dstw, float* __restrict__ dstb,
                        const int* __restrict__ flags) {
    int g = blockIdx.x * 256 + threadIdx.x;
    int f32in = flags[0];
    if (g < 106496) {
        const void* src; int off;
        if (g < 65536) { int n = g >> 8, k = g & 255;
            src = (k < 128) ? w1l : w1r; off = n * 128 + (k & 127); }
        else if (g < 81920) { src = w2l; off = g - 65536; }
        else if (g < 98304) { src = w2r; off = g - 81920; }
        else                { src = wd;  off = g - 98304; }
        dstw[g] = f32in ? (uint16_t)f2bf(((const float*)src)[off])
                        : ((const uint16_t*)src)[off];
    } else if (g < 106944) {
        int o = g - 106496;
        const void* src; int off;
        if (o < 256)      { src = b1; off = o; }
        else if (o < 320) { src = b2; off = o - 256; }
        else              { src = bd; off = o - 320; }
        dstb[o] = f32in ? ((const float*)src)[off] : bf2f(((const uint16_t*)src)[off]);
    }
}

// Stage concat-x as bf16 into the P/R buffers: x[v][0..63] -> Px row v,
// x[v][64..127] -> Rx row v. (Overwritten by real P/R in k_gemm1's epilogue.)
__global__ void k_build_x(const void* xm, const void* xp, uint16_t* __restrict__ Px,
                          uint16_t* __restrict__ Rx, const int* __restrict__ flags) {
    int idx = blockIdx.x * 256 + threadIdx.x;
    if (idx >= NTOT * IND) return;
    int v = idx >> 7, d = idx & 127;
    int f32in = flags[0];
    uint16_t val;
    if (v < NMEM) {
        if (d < DMEM) {
            size_t o = (size_t)v * DMEM + d;
            val = f32in ? (uint16_t)f2bf(((const float*)xm)[o]) : ((const uint16_t*)xm)[o];
        } else val = 0;
    } else {
        size_t o = (size_t)(v - NMEM) * DPRV + d;
        val = f32in ? (uint16_t)f2bf(((const float*)xp)[o]) : ((const uint16_t*)xp)[o];
    }
    if (d < 64) Px[(size_t)v * 64 + d] = val;
    else        Rx[(size_t)v * 64 + (d - 64)] = val;
}

// ---------------- CSR build (verified) ----------------
__global__ void k_count(const int* __restrict__ ei, int* __restrict__ cnt,
                        const int* __restrict__ flags) {
    int j = blockIdx.x * 256 + threadIdx.x;
    if (j >= NEDGE) return;
    int i64 = flags[1];
    int p = ld_ei(ei, j, i64), m = ld_ei(ei, NEDGE + j, i64);
    atomicAdd(&cnt[NMEM + m], 1);
    atomicAdd(&cnt[p], 1);
}
__global__ void k_scan1(int* __restrict__ cnt, int* __restrict__ bsum) {
    __shared__ int s[1024];
    int t = threadIdx.x, i = blockIdx.x * 1024 + t;
    int v = (i < NTOT) ? cnt[i] : 0;
    s[t] = v; __syncthreads();
    for (int off = 1; off < 1024; off <<= 1) {
        int x = (t >= off) ? s[t - off] : 0;
        __syncthreads();
        s[t] += x;
        __syncthreads();
    }
    if (i < NTOT) cnt[i] = s[t] - v;
    if (t == 1023) bsum[blockIdx.x] = s[1023];
}
__global__ void k_scan2(int* __restrict__ bsum) {
    __shared__ int s[128];
    int t = threadIdx.x;
    int v = (t < 98) ? bsum[t] : 0;
    s[t] = v; __syncthreads();
    for (int off = 1; off < 128; off <<= 1) {
        int x = (t >= off) ? s[t - off] : 0;
        __syncthreads();
        s[t] += x;
        __syncthreads();
    }
    if (t < 98) bsum[t] = s[t] - v;
}
__global__ void k_scan3(int* __restrict__ cnt, const int* __restrict__ bsum,
                        int* __restrict__ row_start) {
    int i = blockIdx.x * 1024 + threadIdx.x;
    if (i >= NTOT) return;
    int rs = cnt[i] + bsum[i >> 10];
    row_start[i] = rs;
    cnt[i] = rs;
    if (i == 0) row_start[NTOT] = 2 * NEDGE;
}
__global__ void k_fill(const int* __restrict__ ei, int* __restrict__ cursor,
                       int* __restrict__ colg, const int* __restrict__ flags) {
    int j = blockIdx.x * 256 + threadIdx.x;
    if (j >= NEDGE) return;
    int i64 = flags[1];
    int p = ld_ei(ei, j, i64), m = ld_ei(ei, NEDGE + j, i64);
    int pos1 = atomicAdd(&cursor[NMEM + m], 1); colg[pos1] = p;
    int pos2 = atomicAdd(&cursor[p], 1);        colg[pos2] = NMEM + m;
}

// agg1: A1[v] = mean over nb(v) of bf16 x rows (in Px|Rx). Wave = 4 slots x 16 cgs.
__global__ __launch_bounds__(256) void k_agg1(const uint16_t* __restrict__ Px,
                                              const uint16_t* __restrict__ Rx,
                                              const int* __restrict__ row_start,
                                              const int* __restrict__ colg,
                                              uint16_t* __restrict__ A1) {
    int v = blockIdx.x * 4 + (threadIdx.x >> 6);
    int lane = threadIdx.x & 63;
    int slot = lane >> 4, cg = lane & 15;
    const uint16_t* base = (cg < 8) ? Px : Rx;
    int co = (cg & 7) * 8;
    int start = row_start[v], end = row_start[v + 1];
    float a[8] = {0.f, 0.f, 0.f, 0.f, 0.f, 0.f, 0.f, 0.f};
    for (int b = start + slot; b < end; b += 4) {
        int src = colg[b];
        union { uint4 q; uint16_t u[8]; } f;
        f.q = *(const uint4*)(base + (size_t)src * 64 + co);
#pragma unroll
        for (int i = 0; i < 8; i++) a[i] += bf2f(f.u[i]);
    }
#pragma unroll
    for (int i = 0; i < 8; i++) {
        a[i] += __shfl_xor(a[i], 16);
        a[i] += __shfl_xor(a[i], 32);
    }
    if (slot == 0) {
        float inv = 1.0f / (float)max(end - start, 1);
        union { uint4 q; uint16_t u[8]; } o;
#pragma unroll
        for (int i = 0; i < 8; i++) o.u[i] = (uint16_t)f2bf(a[i] * inv);
        *(uint4*)(A1 + (size_t)v * 128 + cg * 8) = o.q;
    }
}

// GEMM1 (MFMA, fused): per wave 16 rows.
//   h = relu([A1 | x] @ W1cat^T + b1)   (LDS tile)
//   P = h @ W2l^T ; R = h @ W2r^T + b2  (overwrite the x staging rows)
// All A-fragments hoisted to registers; __launch_bounds__(256,2) gives the
// allocator 256 VGPRs so the 16 B-loads per ks stay in flight.
__global__ __launch_bounds__(256, 2) void k_gemm1(const uint16_t* __restrict__ A1,
                                                  const uint16_t* __restrict__ canonb,
                                                  const float* __restrict__ biasf,
                                                  uint16_t* __restrict__ P,
                                                  uint16_t* __restrict__ R) {
    __shared__ uint16_t hl[4][16][264];
    int wave = threadIdx.x >> 6, lane = threadIdx.x & 63;
    int m16 = lane & 15, quad = lane >> 4;
    int row0 = (blockIdx.x * 4 + wave) * 16;
    int arow = min(row0 + m16, NTOT - 1);
    v8bf afr[8];
#pragma unroll
    for (int ks = 0; ks < 4; ks++)
        afr[ks] = *(const v8bf*)(A1 + (size_t)arow * 128 + ks * 32 + quad * 8);
    afr[4] = *(const v8bf*)(P + (size_t)arow * 64 + quad * 8);
    afr[5] = *(const v8bf*)(P + (size_t)arow * 64 + 32 + quad * 8);
    afr[6] = *(const v8bf*)(R + (size_t)arow * 64 + quad * 8);
    afr[7] = *(const v8bf*)(R + (size_t)arow * 64 + 32 + quad * 8);
    f32x4 acc[16];
#pragma unroll
    for (int i = 0; i < 16; i++) acc[i] = (f32x4){0.f, 0.f, 0.f, 0.f};
#pragma unroll
    for (int ks = 0; ks < 8; ks++) {
#pragma unroll
        for (int nt = 0; nt < 16; nt++) {
            v8bf b = *(const v8bf*)(canonb + (size_t)(nt * 16 + m16) * 256 + ks * 32 + quad * 8);
            acc[nt] = __builtin_amdgcn_mfma_f32_16x16x32_bf16(afr[ks], b, acc[nt], 0, 0, 0);
        }
    }
#pragma unroll
    for (int nt = 0; nt < 16; nt++) {
        int col = nt * 16 + m16;
        float bia = biasf[col];
#pragma unroll
        for (int r = 0; r < 4; r++)
            hl[wave][quad * 4 + r][col] = (uint16_t)f2bf(fmaxf(acc[nt][r] + bia, 0.f));
    }
    v8bf hfr[8];
#pragma unroll
    for (int ks = 0; ks < 8; ks++)
        hfr[ks] = *(const v8bf*)&hl[wave][m16][ks * 32 + quad * 8];
    f32x4 accP[4], accR[4];
#pragma unroll
    for (int i = 0; i < 4; i++) {
        accP[i] = (f32x4){0.f, 0.f, 0.f, 0.f};
        accR[i] = (f32x4){0.f, 0.f, 0.f, 0.f};
    }
#pragma unroll
    for (int ks = 0; ks < 8; ks++) {
#pragma unroll
        for (int nt = 0; nt < 4; nt++) {
            v8bf bl = *(const v8bf*)(canonb + 65536 + (size_t)(nt * 16 + m16) * 256 + ks * 32 + quad * 8);
            v8bf br = *(const v8bf*)(canonb + 81920 + (size_t)(nt * 16 + m16) * 256 + ks * 32 + quad * 8);
            accP[nt] = __builtin_amdgcn_mfma_f32_16x16x32_bf16(hfr[ks], bl, accP[nt], 0, 0, 0);
            accR[nt] = __builtin_amdgcn_mfma_f32_16x16x32_bf16(hfr[ks], br, accR[nt], 0, 0, 0);
        }
    }
#pragma unroll
    for (int nt = 0; nt < 4; nt++) {
        int col = nt * 16 + m16;
        float b2 = biasf[256 + col];
#pragma unroll
        for (int r = 0; r < 4; r++) {
            int row = row0 + quad * 4 + r;
            if (row < NTOT) {
                P[(size_t)row * 64 + col] = (uint16_t)f2bf(accP[nt][r]);
                R[(size_t)row * 64 + col] = (uint16_t)f2bf(accR[nt][r] + b2);
            }
        }
    }
}

// agg2z: Z[v] = R[v] + mean of P rows over nb(v). Wave = 8 slots x 8 cgs.
__global__ __launch_bounds__(256) void k_agg2z(const uint16_t* __restrict__ P,
                                               const uint16_t* __restrict__ R,
                                               const int* __restrict__ row_start,
                                               const int* __restrict__ colg,
                                               uint16_t* __restrict__ Z) {
    int v = blockIdx.x * 4 + (threadIdx.x >> 6);
    int lane = threadIdx.x & 63;
    int slot = lane >> 3, cg = lane & 7;
    int start = row_start[v], end = row_start[v + 1];
    float a[8] = {0.f, 0.f, 0.f, 0.f, 0.f, 0.f, 0.f, 0.f};
    for (int b = start + slot; b < end; b += 8) {
        int src = colg[b];
        union { uint4 q; uint16_t u[8]; } f;
        f.q = *(const uint4*)(P + (size_t)src * 64 + cg * 8);
#pragma unroll
        for (int i = 0; i < 8; i++) a[i] += bf2f(f.u[i]);
    }
#pragma unroll
    for (int i = 0; i < 8; i++) {
        a[i] += __shfl_xor(a[i], 8);
        a[i] += __shfl_xor(a[i], 16);
        a[i] += __shfl_xor(a[i], 32);
    }
    if (slot == 0) {
        float inv = 1.0f / (float)max(end - start, 1);
        union { uint4 q; uint16_t u[8]; } rr, o;
        rr.q = *(const uint4*)(R + (size_t)v * 64 + cg * 8);
#pragma unroll
        for (int i = 0; i < 8; i++)
            o.u[i] = (uint16_t)f2bf(a[i] * inv + bf2f(rr.u[i]));
        *(uint4*)(Z + (size_t)v * 64 + cg * 8) = o.q;
    }
}

// GEMM3 (MFMA): x_hat = Z @ Wd^T + bd -> f32 d_out [NTOT][128].
__global__ __launch_bounds__(256, 2) void k_gemm3(const uint16_t* __restrict__ Z,
                                                  const uint16_t* __restrict__ canonb,
                                                  const float* __restrict__ biasf,
                                                  float* __restrict__ outf) {
    int wave = threadIdx.x >> 6, lane = threadIdx.x & 63;
    int m16 = lane & 15, quad = lane >> 4;
    int row0 = (blockIdx.x * 4 + wave) * 16;
    int arow = min(row0 + m16, NTOT - 1);
    v8bf a0 = *(const v8bf*)(Z + (size_t)arow * 64 + quad * 8);
    v8bf a1 = *(const v8bf*)(Z + (size_t)arow * 64 + 32 + quad * 8);
    f32x4 acc[8];
#pragma unroll
    for (int i = 0; i < 8; i++) acc[i] = (f32x4){0.f, 0.f, 0.f, 0.f};
#pragma unroll
    for (int nt = 0; nt < 8; nt++) {
        v8bf b0 = *(const v8bf*)(canonb + 98304 + (size_t)(nt * 16 + m16) * 64 + quad * 8);
        v8bf b1 = *(const v8bf*)(canonb + 98304 + (size_t)(nt * 16 + m16) * 64 + 32 + quad * 8);
        acc[nt] = __builtin_amdgcn_mfma_f32_16x16x32_bf16(a0, b0, acc[nt], 0, 0, 0);
        acc[nt] = __builtin_amdgcn_mfma_f32_16x16x32_bf16(a1, b1, acc[nt], 0, 0, 0);
    }
#pragma unroll
    for (int nt = 0; nt < 8; nt++) {
        int col = nt * 16 + m16;
        float bia = biasf[320 + col];
#pragma unroll
        for (int r = 0; r < 4; r++) {
            int row = row0 + quad * 4 + r;
            if (row < NTOT) outf[(size_t)row * 128 + col] = acc[nt][r] + bia;
        }
    }
}

// edge_logits[j] = dot64(Z[NM+p], Z[m]) -> f32; 8 lanes/edge.
__global__ __launch_bounds__(256) void k_logits(const int* __restrict__ ei,
                                                const uint16_t* __restrict__ Z,
                                                float* __restrict__ out,
                                                const int* __restrict__ flags) {
    int t = blockIdx.x * 256 + threadIdx.x;
    int j = t >> 3, sub = t & 7;
    if (j >= NEDGE) return;
    int i64 = flags[1];
    int p = ld_ei(ei, j, i64), m = ld_ei(ei, NEDGE + j, i64);
    union { uint4 q; uint16_t u[8]; } a, b;
    a.q = *(const uint4*)(Z + (size_t)(NMEM + p) * 64 + sub * 8);
    b.q = *(const uint4*)(Z + (size_t)m * 64 + sub * 8);
    float d = 0.f;
#pragma unroll
    for (int i = 0; i < 8; i++) d += bf2f(a.u[i]) * bf2f(b.u[i]);
    d += __shfl_xor(d, 1);
    d += __shfl_xor(d, 2);
    d += __shfl_xor(d, 4);
    if (sub == 0) out[j] = d;
}

// Sentinel path (ws too small).
__global__ void k_zero_out(float* __restrict__ out, int n4) {
    int i = blockIdx.x * 256 + threadIdx.x;
    if (i < n4) ((uint4*)out)[i] = (uint4){0, 0, 0, 0};
}
__global__ void k_sentinel(float* __restrict__ out, const int* __restrict__ flags,
                           int ws_mb) {
    if (blockIdx.x == 0 && threadIdx.x == 0)
        out[0] = 1000.0f + (float)ws_mb + 4096.0f * flags[0] + 8192.0f * flags[1];
}

extern "C" void kernel_launch(void* const* d_in, const int* in_sizes, int n_in,
                              void* d_out, int out_size, void* d_ws, size_t ws_size,
                              hipStream_t stream) {
    const void* xm = d_in[0];
    const void* xp = d_in[1];
    const int*  ei = (const int*)d_in[2];
    float* outf = (float*)d_out;

    const size_t NEED = 73019648;
    if (ws_size < NEED) {
        int* flags = (int*)d_ws;
        k_detect<<<1, 256, 0, stream>>>((const uint16_t*)d_in[3], ei, flags);
        int n4 = out_size / 4;
        k_zero_out<<<(n4 + 255) / 256, 256, 0, stream>>>(outf, n4);
        k_sentinel<<<1, 64, 0, stream>>>(outf, flags, (int)(ws_size >> 20));
        return;
    }

    // Layout (73,019,648 B, proven available):
    char* ws = (char*)d_ws;
    int* colg       = (int*)(ws + 0);              //  8,000,000
    int* cnt        = (int*)(ws + 8000000);        //    400,384 (becomes cursor)
    int* row_start  = (int*)(ws + 8400384);        //    400,384
    int* bsum       = (int*)(ws + 8800768);        //      4,096 (flags at +100 ints)
    int* flags      = (int*)(ws + 8800768) + 100;
    uint16_t* canonb= (uint16_t*)(ws + 8804864);   //    212,992 (bf16 weights)
    float* biasf    = (float*)(ws + 9017856);      //      1,792 (f32 biases)
    uint16_t* A1    = (uint16_t*)(ws + 9019648);   // 25,600,000
    uint16_t* P     = (uint16_t*)(ws + 34619648);  // 12,800,000 (x cols 0-63 -> P)
    uint16_t* R     = (uint16_t*)(ws + 47419648);  // 12,800,000 (x cols 64-127 -> R)
    uint16_t* Z     = (uint16_t*)(ws + 60219648);  // 12,800,000

    k_detect<<<1, 256, 0, stream>>>((const uint16_t*)d_in[3], ei, flags);
    k_canon<<<418, 256, 0, stream>>>(d_in[3], d_in[4], d_in[6], d_in[7], d_in[9],
                                     d_in[5], d_in[8], d_in[10], canonb, biasf, flags);
    k_build_x<<<(NTOT * IND + 255) / 256, 256, 0, stream>>>(xm, xp, P, R, flags);
    hipMemsetAsync(cnt, 0, NTOT * sizeof(int), stream);
    k_count<<<(NEDGE + 255) / 256, 256, 0, stream>>>(ei, cnt, flags);
    k_scan1<<<98, 1024, 0, stream>>>(cnt, bsum);
    k_scan2<<<1, 128, 0, stream>>>(bsum);
    k_scan3<<<98, 1024, 0, stream>>>(cnt, bsum, row_start);
    k_fill<<<(NEDGE + 255) / 256, 256, 0, stream>>>(ei, cnt, colg, flags);
    k_agg1<<<NTOT / 4, 256, 0, stream>>>(P, R, row_start, colg, A1);
    k_gemm1<<<1563, 256, 0, stream>>>(A1, canonb, biasf, P, R);
    k_agg2z<<<NTOT / 4, 256, 0, stream>>>(P, R, row_start, colg, Z);
    k_gemm3<<<1563, 256, 0, stream>>>(Z, canonb, biasf, outf);
    k_logits<<<NEDGE * 8 / 256, 256, 0, stream>>>(ei, Z, outf + 12800000, flags);
}